// Round 13
// baseline (307.121 us; speedup 1.0000x reference)
//
#include <hip/hip_runtime.h>
#include <math.h>

#define TPB 256
#define NNEG 2048
#define D 128
#define RPB 64               // rows per block (4 waves x 16)
#define CHUNK 64             // negs per staged chunk (16 KB)
#define NCH (NNEG / CHUNK)   // 32 chunks
#define L2E 1.44269504088896340736f

typedef __attribute__((ext_vector_type(8))) short bf16x8;
typedef __attribute__((ext_vector_type(4))) float f32x4;

#define MFMA16 __builtin_amdgcn_mfma_f32_16x16x32_bf16

static __device__ __forceinline__ unsigned int f2bf(float f) {
    unsigned int u = __float_as_uint(f);
    return (u + 0x7FFFu + ((u >> 16) & 1u)) >> 16;
}
static __device__ __forceinline__ float bfround(float f) {
    unsigned int u = __float_as_uint(f);
    return __uint_as_float((u + 0x7FFFu + ((u >> 16) & 1u)) & 0xFFFF0000u);
}
static __device__ __forceinline__ unsigned int pk2(float x, float y) {
    return f2bf(x) | (f2bf(y) << 16);
}

static __device__ __forceinline__ void stage16(const void* g, void* l) {
    __builtin_amdgcn_global_load_lds(
        (const __attribute__((address_space(1))) unsigned int*)g,
        (__attribute__((address_space(3))) unsigned int*)l, 16, 0, 0);
}

// ---------------- clear ----------------
__global__ __launch_bounds__(TPB) void sspe_clear(unsigned int* __restrict__ bm, int words) {
    const int i = blockIdx.x * TPB + threadIdx.x;
    if (i < words) bm[i] = 0u;
}

// ---------------- prep ----------------
__global__ __launch_bounds__(TPB) void sspe_prep(
    const float* __restrict__ embed,
    const float* __restrict__ sprobs,
    const int* __restrict__ sidx,
    unsigned int* __restrict__ en_bf,
    float* __restrict__ ln_samp,
    unsigned int* __restrict__ bitmap)
{
    const int t = threadIdx.x;
    const int wave = t >> 6;
    const int lane = t & 63;
    const int j = blockIdx.x * 4 + wave;
    const int idx = sidx[j];

    float2 v = reinterpret_cast<const float2*>(embed)[(size_t)idx * 64 + lane];
    float ss = v.x * v.x + v.y * v.y;
    ss += __shfl_xor(ss, 1);
    ss += __shfl_xor(ss, 2);
    ss += __shfl_xor(ss, 4);
    ss += __shfl_xor(ss, 8);
    ss += __shfl_xor(ss, 16);
    ss += __shfl_xor(ss, 32);
    const float rinv = 1.0f / fmaxf(sqrtf(ss), 1e-12f);
    en_bf[(size_t)j * 64 + lane] = pk2(v.x * rinv, v.y * rinv);
    if (lane == 0) {
        ln_samp[j] = logf(sprobs[idx] + 1e-10f);
        atomicOr(&bitmap[idx >> 5], 1u << (idx & 31));
    }
}

// ---------------- main (ablation template) ----------------
// V=0 full | V=1 no-epilogue | V=2 no-MFMA | V=3 no-staging
template<int V>
__global__ __launch_bounds__(TPB, 4) void sspe_main(
    const float* __restrict__ hidden,
    const int* __restrict__ y,
    const float* __restrict__ embed,
    const float* __restrict__ sprobs,
    const float* __restrict__ ltemp,
    const unsigned int* __restrict__ en_bf,
    const float* __restrict__ ln_samp,
    float* __restrict__ pos_adj,
    float* __restrict__ lsum_out)
{
    const int t = threadIdx.x;
    const int wave = t >> 6;
    const int lane = t & 63;
    const int rb = blockIdx.x * RPB;

    __shared__ __align__(16) unsigned char smem[2 * CHUNK * 256];  // 32 KB
    __shared__ float lk_lds[NNEG];                                  // 8 KB

    const float temp = __builtin_amdgcn_exp2f(fminf(ltemp[0], 4.6f) * L2E);
    const float t2 = temp * L2E;
    const float Mln = temp + 14.0f;   // uniform safe max
    const float M2 = Mln * L2E;

    const int g = lane >> 4;
    const int rl = lane & 15;

    // ---- Prologue: normalize 16 rows/wave -> bf16 into smem (swizzled) ----
    #pragma unroll 1
    for (int i = 0; i < 16; i += 4) {
        float2 h2[4], e2[4];
        int yi[4];
        #pragma unroll
        for (int u = 0; u < 4; ++u) {
            const int lr = wave * 16 + i + u;
            h2[u] = reinterpret_cast<const float2*>(hidden)[(size_t)(rb + lr) * 64 + lane];
            yi[u] = y[rb + lr];
        }
        #pragma unroll
        for (int u = 0; u < 4; ++u)
            e2[u] = reinterpret_cast<const float2*>(embed)[(size_t)yi[u] * 64 + lane];
        float ss[4], es[4], dt[4];
        #pragma unroll
        for (int u = 0; u < 4; ++u) {
            ss[u] = h2[u].x * h2[u].x + h2[u].y * h2[u].y;
            es[u] = e2[u].x * e2[u].x + e2[u].y * e2[u].y;
            dt[u] = h2[u].x * e2[u].x + h2[u].y * e2[u].y;
        }
        #pragma unroll
        for (int m = 1; m <= 32; m <<= 1)
            #pragma unroll
            for (int u = 0; u < 4; ++u) {
                ss[u] += __shfl_xor(ss[u], m);
                es[u] += __shfl_xor(es[u], m);
                dt[u] += __shfl_xor(dt[u], m);
            }
        #pragma unroll
        for (int u = 0; u < 4; ++u) {
            const int lr = wave * 16 + i + u;
            const float rinv = 1.0f / fmaxf(sqrtf(ss[u]), 1e-12f);
            *reinterpret_cast<unsigned int*>(
                smem + lr * 256 + ((lane * 4) ^ ((lr & 7) << 4)))
                = pk2(h2[u].x * rinv, h2[u].y * rinv);
            if (lane == 0)
                pos_adj[rb + lr] = dt[u] * rinv * (1.0f / fmaxf(sqrtf(es[u]), 1e-12f)) * temp
                                   - logf(sprobs[yi[u]] + 1e-10f);
        }
    }
    for (int k = t; k < NNEG; k += TPB) lk_lds[k] = ln_samp[k];
    __syncthreads();

    // ---- A fragments: one 16-row tile per wave ----
    bf16x8 A[4];
    {
        const int row = wave * 16 + rl;
        const int rx = (rl & 7) << 4;
        #pragma unroll
        for (int ks = 0; ks < 4; ++ks)
            A[ks] = *reinterpret_cast<const bf16x8*>(
                smem + row * 256 + ((ks * 64 + (g << 4)) ^ rx));
    }
    __syncthreads();   // A reads done before restaging over smem

    // Fragment-order staging (conflict-free, proven R6/R9/R12): region
    // d = nt*4+ks holds at byte L*16 exactly the fragment lane L reads.
    unsigned int soff[4];
    #pragma unroll
    for (int i = 0; i < 4; ++i) {
        const int d = wave * 4 + i;
        soff[i] = (unsigned int)(((d >> 2) * 16 + rl) * 256 + (d & 3) * 64 + g * 16);
    }
    const unsigned char* en = reinterpret_cast<const unsigned char*>(en_bf);

    #pragma unroll
    for (int i = 0; i < 4; ++i)
        stage16(en + soff[i], smem + (wave * 4 + i) * 1024);

    float l[4] = {0.f, 0.f, 0.f, 0.f};

    // ---- Main loop: 32 chunks of 64 negs, double-buffered ----
    #pragma unroll 1
    for (int ch = 0; ch < NCH; ++ch) {
        const int cur = (ch & 1) << 14;
        __syncthreads();   // stage(ch) drained & visible

        if (V != 3 && ch + 1 < NCH) {
            const unsigned char* enn = en + (size_t)(ch + 1) * 16384;
            #pragma unroll
            for (int i = 0; i < 4; ++i)
                stage16(enn + soff[i], smem + (cur ^ 16384) + (wave * 4 + i) * 1024);
        }

        const unsigned char* bb = smem + cur + lane * 16;
        #pragma unroll
        for (int nt = 0; nt < 4; ++nt) {
            f32x4 c = {0.f, 0.f, 0.f, 0.f};
            #pragma unroll
            for (int ks = 0; ks < 4; ++ks) {
                const bf16x8 b = *reinterpret_cast<const bf16x8*>(bb + (nt * 4 + ks) * 1024);
                if (V == 2) {
                    union { bf16x8 s; f32x4 f; } ub; ub.s = b;
                    c += ub.f;                     // keep ds_read live, no MFMA
                } else {
                    c = MFMA16(A[ks], b, c, 0, 0, 0);
                }
            }
            if (V == 1) {
                #pragma unroll
                for (int j = 0; j < 4; ++j) l[j] += c[j];   // no exp epilogue
            } else {
                const float nl = fmaf(lk_lds[ch * 64 + nt * 16 + rl], -L2E, -M2);
                #pragma unroll
                for (int j = 0; j < 4; ++j)
                    l[j] += __builtin_amdgcn_exp2f(fmaf(c[j], t2, nl));
            }
        }
    }

    // ---- Reduce across the 16 neg-columns; store per-row sums ----
    #pragma unroll
    for (int j = 0; j < 4; ++j) {
        float v = l[j];
        v += __shfl_xor(v, 1);
        v += __shfl_xor(v, 2);
        v += __shfl_xor(v, 4);
        v += __shfl_xor(v, 8);
        l[j] = v;
    }
    if (rl == 0) {
        float* dst = lsum_out + rb + wave * 16 + g * 4;
        #pragma unroll
        for (int j = 0; j < 4; ++j) dst[j] = l[j];
    }
}

// ---------------- rows: subtract collision terms, per-row loss ----------------
__global__ __launch_bounds__(TPB) void sspe_rows(
    const int* __restrict__ y,
    const float* __restrict__ ltemp,
    const int* __restrict__ sidx,
    const float* __restrict__ hidden,
    const unsigned int* __restrict__ en_bf,
    const float* __restrict__ ln_samp,
    const unsigned int* __restrict__ bitmap,
    const float* __restrict__ pos_adj,
    const float* __restrict__ lsum,
    int nrows,
    float2* __restrict__ partials)
{
    __shared__ int ssi[NNEG];
    __shared__ float2 red2[4];
    const int t = threadIdx.x;
    const int wave = t >> 6;
    const int lane = t & 63;
    const int r = blockIdx.x * TPB + t;

    for (int k = t; k < NNEG; k += TPB) ssi[k] = sidx[k];
    __syncthreads();

    const float temp = __builtin_amdgcn_exp2f(fminf(ltemp[0], 4.6f) * L2E);
    const float t2 = temp * L2E;
    const float Mln = temp + 14.0f;
    const float M2 = Mln * L2E;

    const int yr = y[r];
    float w = (yr != 0) ? 1.0f : 0.0f;
    float s = lsum[r];

    const bool hit = (w > 0.0f) && ((bitmap[yr >> 5] >> (yr & 31)) & 1u);
    unsigned long long m = __ballot(hit);
    while (m) {
        const int b = (int)(__ffsll((long long)m) - 1); m &= m - 1;
        const int yb = __shfl(yr, b);
        const int rB = __shfl(r, b);
        const float2 h2 = reinterpret_cast<const float2*>(hidden)[(size_t)rB * 64 + lane];
        float hs = h2.x * h2.x + h2.y * h2.y;
        #pragma unroll
        for (int k = 1; k <= 32; k <<= 1) hs += __shfl_xor(hs, k);
        const float rinv = 1.0f / fmaxf(sqrtf(hs), 1e-12f);
        const float hb0 = bfround(h2.x * rinv);
        const float hb1 = bfround(h2.y * rinv);
        float corr = 0.0f;
        for (int k = 0; k < NNEG; k += 64) {
            const int sj = ssi[k + lane];
            unsigned long long mm = __ballot(sj == yb);
            while (mm) {
                const int jj = (int)(__ffsll((long long)mm) - 1); mm &= mm - 1;
                const int j = k + jj;
                const unsigned int eu = en_bf[(size_t)j * 64 + lane];
                const float e0 = __uint_as_float(eu << 16);
                const float e1 = __uint_as_float(eu & 0xFFFF0000u);
                float d = hb0 * e0 + hb1 * e1;
                #pragma unroll
                for (int q = 1; q <= 32; q <<= 1) d += __shfl_xor(d, q);
                corr += __builtin_amdgcn_exp2f(fmaf(d, t2, fmaf(ln_samp[j], -L2E, -M2)));
            }
        }
        if (lane == b) s -= corr;
    }
    s = fmaxf(s, 0.0f);

    const float pa = pos_adj[r];
    const float stot = s + __builtin_amdgcn_exp2f(fmaf(pa, L2E, -M2));
    float per = (Mln + logf(stot) - pa) * w;

    #pragma unroll
    for (int msk = 1; msk < 64; msk <<= 1) {
        per += __shfl_xor(per, msk);
        w += __shfl_xor(w, msk);
    }
    if (lane == 0) red2[wave] = make_float2(per, w);
    __syncthreads();
    if (t == 0) {
        const float2 a = red2[0], b2 = red2[1], c = red2[2], d2 = red2[3];
        partials[blockIdx.x] = make_float2(a.x + b2.x + c.x + d2.x,
                                           a.y + b2.y + c.y + d2.y);
    }
}

// ---------------- finalize ----------------
__global__ __launch_bounds__(TPB) void sspe_finalize(
    const float2* __restrict__ partials, int n, float* __restrict__ out)
{
    __shared__ float ssum[TPB];
    __shared__ float scnt[TPB];
    const int t = threadIdx.x;
    float s = 0.0f, c = 0.0f;
    for (int i = t; i < n; i += TPB) {
        const float2 p = partials[i];
        s += p.x; c += p.y;
    }
    ssum[t] = s; scnt[t] = c;
    __syncthreads();
    for (int k = TPB / 2; k > 0; k >>= 1) {
        if (t < k) { ssum[t] += ssum[t + k]; scnt[t] += scnt[t + k]; }
        __syncthreads();
    }
    if (t == 0) out[0] = ssum[0] / fmaxf(scnt[0], 1.0f);
}

extern "C" void kernel_launch(void* const* d_in, const int* in_sizes, int n_in,
                              void* d_out, int out_size, void* d_ws, size_t ws_size,
                              hipStream_t stream) {
    const float* hidden = (const float*)d_in[0];
    const int*   yv     = (const int*)d_in[1];
    const float* embed  = (const float*)d_in[2];
    const float* sprobs = (const float*)d_in[3];
    const int*   sidx   = (const int*)d_in[4];
    const float* ltemp  = (const float*)d_in[5];
    float* out = (float*)d_out;

    const int nrows = in_sizes[1];                 // 65536
    const int vocab = in_sizes[3];                 // 100000
    const int bmw = (vocab + 31) / 32;
    const int nblocks = nrows / RPB;               // 1024

    char* w = (char*)d_ws;
    size_t off = 0;
    unsigned int* en_bf = (unsigned int*)(w + off); off += (size_t)NNEG * D * 2;      // 512 KB
    float* ln_samp      = (float*)(w + off);        off += (size_t)NNEG * 4;          // 8 KB
    float* pos_adj      = (float*)(w + off);        off += (size_t)nrows * 4;         // 256 KB
    float* lsum         = (float*)(w + off);        off += (size_t)nrows * 4;         // 256 KB
    float* lsum_scr     = (float*)(w + off);        off += (size_t)nrows * 4;         // 256 KB
    float2* partials    = (float2*)(w + off);       off += (size_t)(nrows / TPB) * 8; // 2 KB
    unsigned int* bitmap = (unsigned int*)(w + off);

    sspe_clear<<<(bmw + TPB - 1) / TPB, TPB, 0, stream>>>(bitmap, bmw);
    sspe_prep<<<NNEG / 4, TPB, 0, stream>>>(embed, sprobs, sidx, en_bf, ln_samp, bitmap);

    // Ablation dispatches (outputs to scratch; rocprof separates them)
    sspe_main<1><<<nblocks, TPB, 0, stream>>>(hidden, yv, embed, sprobs, ltemp,
                                              en_bf, ln_samp, pos_adj, lsum_scr);
    sspe_main<2><<<nblocks, TPB, 0, stream>>>(hidden, yv, embed, sprobs, ltemp,
                                              en_bf, ln_samp, pos_adj, lsum_scr);
    sspe_main<3><<<nblocks, TPB, 0, stream>>>(hidden, yv, embed, sprobs, ltemp,
                                              en_bf, ln_samp, pos_adj, lsum_scr);
    // Real computation (last, writes the authoritative lsum)
    sspe_main<0><<<nblocks, TPB, 0, stream>>>(hidden, yv, embed, sprobs, ltemp,
                                              en_bf, ln_samp, pos_adj, lsum);

    sspe_rows<<<nrows / TPB, TPB, 0, stream>>>(yv, ltemp, sidx, hidden, en_bf, ln_samp,
                                               bitmap, pos_adj, lsum, nrows, partials);
    sspe_finalize<<<1, TPB, 0, stream>>>(partials, nrows / TPB, out);
}